// Round 2
// 94.397 us; speedup vs baseline: 1.0341x; 1.0341x over previous
//
#include <hip/hip_runtime.h>
#include <hip/hip_bf16.h>

typedef __bf16 bf16x8 __attribute__((ext_vector_type(8)));
typedef short  s16x4  __attribute__((ext_vector_type(4)));
typedef float  f32x16 __attribute__((ext_vector_type(16)));

constexpr int QN  = 128;   // query rows
constexpr int KN  = 2048;  // memory rows
constexpr int D5  = 768;
constexpr int SL  = 32;    // seq_len (t and s extent)
constexpr int ZD  = 24;    // per-token sub-dim
constexpr int KCH = 16;    // k's per block

// Exact-K tail: d16-23 is K=8, use legacy 32x32x8 bf16 MFMA (present on gfx950,
// ISA §10) instead of a zero-padded K=16. Guarded so a missing builtin falls
// back to the padded path.
#if __has_builtin(__builtin_amdgcn_mfma_f32_32x32x8bf16_1k)
#define HAVE_MFMA_X8 1
#else
#define HAVE_MFMA_X8 0
#endif

static __device__ __forceinline__ float max3f(float a, float b, float c) {
    return fmaxf(fmaxf(a, b), c);   // fuses to v_max3_f32
}

// 16-element register max as a max3 tree
static __device__ __forceinline__ float redmax16(const f32x16& a) {
    float x0 = max3f(a[0],  a[1],  a[2]);
    float x1 = max3f(a[3],  a[4],  a[5]);
    float x2 = max3f(a[6],  a[7],  a[8]);
    float x3 = max3f(a[9],  a[10], a[11]);
    float x4 = max3f(a[12], a[13], a[14]);
    float y0 = max3f(x0, x1, x2);
    float y1 = max3f(x3, x4, a[15]);
    return fmaxf(y0, y1);
}

#if HAVE_MFMA_X8
static __device__ __forceinline__ short f2bfbits(float x) {
    __bf16 b = (__bf16)x;
    return __builtin_bit_cast(short, b);
}
#endif

// Per-pair: S[t][s] via mfma_f32_32x32x16_bf16 (d0-15) + exact-K tail (d16-23),
// and S^T via the swapped-operand pair, so BOTH max-pools are per-lane register
// reductions in the C layout (col=lane&31, rows span the 16 acc regs + halves).
//
// R4: (a) accumulators pinned to arch VGPRs (empty asm "+v") — kills the
// v_accvgpr_read copy tax feeding the max trees (VGPR_Count was 44: accs were
// in AGPRs). (b) K-tail via 32x32x8 MFMA: exact K=8, -25% matrix-pipe cycles,
// and all 64 lanes hold valid tail fragments -> no divergent bK1 load, no
// per-pair re-zeroing. (c) fallback path reads bK1 unconditionally (h==1 lanes
// garbage-tolerant: those rows multiply aQ1's zeroed K-rows in both MFMAs).
__global__ __launch_bounds__(256, 4) void matcher_kernel(const float* __restrict__ tgt,
                                                         const float* __restrict__ mem,
                                                         float* __restrict__ out)
{
    // K fragments: per k, chunk0 = 64 lanes x 16B (d0-15), chunk1 = 32 s x 16B
    // (d16-23). 1536B per k.
    __shared__ __align__(16) __bf16 Kf[KCH * 768];     // 24 KB
    // Per-wave epilogue buffer: [pair][32 swizzled maxes]. 2 KB per wave.
    __shared__ float vbuf[4][KCH * 32];                // 8 KB  (total 32 KB)

    const int tid = threadIdx.x;
    const int kc  = blockIdx.x;   // 0..127
    const int qg  = blockIdx.y;   // 0..31
    const int k0  = kc * KCH;

    // ---- stage K chunk: fp32 -> bf16, MFMA fragment order ----
    for (int r = tid; r < KCH * SL; r += 256) {
        const int kl = r >> 5;
        const int s  = r & 31;
        const float* src = mem + (size_t)(k0 + kl) * D5 + s * ZD;
        float tv[24];
#pragma unroll
        for (int j = 0; j < 6; ++j) ((float4*)tv)[j] = ((const float4*)src)[j];
        bf16x8 a, b, c;
#pragma unroll
        for (int j = 0; j < 8; ++j) {
            a[j] = (__bf16)tv[j];
            b[j] = (__bf16)tv[8 + j];
            c[j] = (__bf16)tv[16 + j];
        }
        __bf16* base = Kf + kl * 768;
        *(bf16x8*)(base +        s * 8)  = a;  // chunk0, lane s      (d 0-7)
        *(bf16x8*)(base + (32 +  s) * 8) = b;  // chunk0, lane s+32   (d 8-15)
        *(bf16x8*)(base + 512 +  s * 8)  = c;  // chunk1, row s       (d 16-23)
    }

    // ---- per-wave Q fragments (registers, live across the whole k-loop) ----
    const int lane = tid & 63;
    const int wv   = tid >> 6;   // 0..3
    const int t    = lane & 31;
    const int h    = lane >> 5;
    const int q    = qg * 4 + wv;

    const float4* p4 = (const float4*)(tgt + (size_t)q * D5 + t * ZD);
    bf16x8 aQ0;
    {
        float4 u0 = p4[2 * h], u1 = p4[2 * h + 1];  // d = h*8 .. h*8+7
        aQ0[0] = (__bf16)u0.x; aQ0[1] = (__bf16)u0.y; aQ0[2] = (__bf16)u0.z; aQ0[3] = (__bf16)u0.w;
        aQ0[4] = (__bf16)u1.x; aQ0[5] = (__bf16)u1.y; aQ0[6] = (__bf16)u1.z; aQ0[7] = (__bf16)u1.w;
    }
#if HAVE_MFMA_X8
    // 32x32x8 A/B fragment: lane holds k = (lane>>5)*4 + j, i.e. d = 16 + h*4 + j.
    s16x4 aQ1;
    {
        float4 w = p4[4 + h];                       // d16-19 (h=0) / d20-23 (h=1)
        aQ1[0] = f2bfbits(w.x); aQ1[1] = f2bfbits(w.y);
        aQ1[2] = f2bfbits(w.z); aQ1[3] = f2bfbits(w.w);
    }
#else
    bf16x8 aQ1;
    if (h == 0) {
        float4 w0 = p4[4], w1 = p4[5];              // d = 16..23
        aQ1[0] = (__bf16)w0.x; aQ1[1] = (__bf16)w0.y; aQ1[2] = (__bf16)w0.z; aQ1[3] = (__bf16)w0.w;
        aQ1[4] = (__bf16)w1.x; aQ1[5] = (__bf16)w1.y; aQ1[6] = (__bf16)w1.z; aQ1[7] = (__bf16)w1.w;
    } else {
#pragma unroll
        for (int j = 0; j < 8; ++j) aQ1[j] = (__bf16)0.0f; // d 24-31 pad
    }
#endif

    // Loop-invariant zero C operand, pinned to arch VGPRs.
    f32x16 zacc;
#pragma unroll
    for (int i = 0; i < 16; ++i) zacc[i] = 0.0f;
    asm volatile("" : "+v"(zacc));

    __syncthreads();

    float* vb = vbuf[wv];

    // ---- pair loop: this wave handles (q, k0+kl) for kl = 0..KCH-1 ----
#pragma unroll
    for (int kl = 0; kl < KCH; ++kl) {
        const __bf16* lb = Kf + kl * 768;
        bf16x8 bK0 = *(const bf16x8*)(lb + lane * 8);
#if HAVE_MFMA_X8
        // tail fragment: K[s][16 + h*4 + j], 8B per lane, all lanes valid
        s16x4 bK1 = *(const s16x4*)(lb + 512 + t * 8 + h * 4);

        // S[t][s]: A=Q (m=t), B=K (n=s)
        f32x16 accS = __builtin_amdgcn_mfma_f32_32x32x16_bf16(aQ0, bK0, zacc, 0, 0, 0);
        accS = __builtin_amdgcn_mfma_f32_32x32x8bf16_1k(aQ1, bK1, accS, 0, 0, 0);
        // S^T[s][t]: A=K (m=s), B=Q (n=t)
        f32x16 accT = __builtin_amdgcn_mfma_f32_32x32x16_bf16(bK0, aQ0, zacc, 0, 0, 0);
        accT = __builtin_amdgcn_mfma_f32_32x32x8bf16_1k(bK1, aQ1, accT, 0, 0, 0);
#else
        // Unconditional read: h==1 lanes duplicate h==0 addresses (LDS broadcast).
        // Their fragment rows (k=8-15 of the tail) only ever multiply aQ1's
        // zeroed half in BOTH MFMAs, so garbage there is harmless.
        bf16x8 bK1 = *(const bf16x8*)(lb + 512 + t * 8);

        f32x16 accS = __builtin_amdgcn_mfma_f32_32x32x16_bf16(aQ0, bK0, zacc, 0, 0, 0);
        accS        = __builtin_amdgcn_mfma_f32_32x32x16_bf16(aQ1, bK1, accS, 0, 0, 0);
        f32x16 accT = __builtin_amdgcn_mfma_f32_32x32x16_bf16(bK0, aQ0, zacc, 0, 0, 0);
        accT        = __builtin_amdgcn_mfma_f32_32x32x16_bf16(bK1, aQ1, accT, 0, 0, 0);
#endif
        // Pin to arch VGPRs so the max trees read them directly (no accvgpr_read).
        asm volatile("" : "+v"(accS), "+v"(accT));

        // accS: col=s=lane&31, regs+halves span t -> max over t = score.max(axis=3)
        // accT: col=t=lane&31, regs+halves span s -> max over s = score.max(axis=2)
        float m1 = redmax16(accS);
        float m2 = redmax16(accT);
        m1 = fmaxf(m1, __shfl_xor(m1, 32));   // two INDEPENDENT half-combines
        m2 = fmaxf(m2, __shfl_xor(m2, 32));
        float v = m1 + m2;                    // per-lane: axis3max[s] + axis2max[t]
        // XOR-swizzled store: pair kl, slot t -> word kl*32 + (t^kl). Conflict-free.
        if (h == 0) vb[(kl << 5) + (t ^ kl)] = v;
    }

    // ---- batched final phase (per wave, no barrier: same-wave LDS reuse) ----
    // Pair p's 32 values summed by lane pair (p, p+16); lanes 32-63 duplicate.
    {
        const int p    = lane & 15;
        const int half = (lane >> 4) & 1;
        float x[16];
#pragma unroll
        for (int i = 0; i < 16; ++i)
            x[i] = vb[(p << 5) + ((half << 4) + i ^ p)];  // conflict-free scalar reads
        // pairwise add tree (full ILP)
        float s0 = (x[0] + x[1]) + (x[2] + x[3]);
        float s1 = (x[4] + x[5]) + (x[6] + x[7]);
        float s2 = (x[8] + x[9]) + (x[10] + x[11]);
        float s3 = (x[12] + x[13]) + (x[14] + x[15]);
        float sum = (s0 + s1) + (s2 + s3);
        sum += __shfl_xor(sum, 16);           // combine halves of the 32-sum
        float r = 1.0f / (1.0f + __expf(-sum * (1.0f / 64.0f)));
        if (lane < 16) {
            const int idx = q * KN + k0 + p;
            out[idx] = r;                     // output 0
            out[idx + QN * KN] = r;           // output 1 (tuple repeats score_p)
        }
    }
}

extern "C" void kernel_launch(void* const* d_in, const int* in_sizes, int n_in,
                              void* d_out, int out_size, void* d_ws, size_t ws_size,
                              hipStream_t stream)
{
    const float* tgt = (const float*)d_in[0];
    const float* mem = (const float*)d_in[1];
    float* out = (float*)d_out;
    dim3 grid(KN / KCH, QN / 4);
    matcher_kernel<<<grid, 256, 0, stream>>>(tgt, mem, out);
}

// Round 3
// 92.187 us; speedup vs baseline: 1.0589x; 1.0240x over previous
//
#include <hip/hip_runtime.h>
#include <hip/hip_bf16.h>

typedef __bf16 bf16x8 __attribute__((ext_vector_type(8)));
typedef short  s16x4  __attribute__((ext_vector_type(4)));
typedef float  f32x16 __attribute__((ext_vector_type(16)));
typedef int    i32x2  __attribute__((ext_vector_type(2)));

constexpr int QN  = 128;   // query rows
constexpr int KN  = 2048;  // memory rows
constexpr int D5  = 768;
constexpr int SL  = 32;    // seq_len (t and s extent)
constexpr int ZD  = 24;    // per-token sub-dim
constexpr int KCH = 16;    // k's per block
constexpr int WPB = 8;     // waves per block (R3: was 4)

#if __has_builtin(__builtin_amdgcn_mfma_f32_32x32x8bf16_1k)
#define HAVE_MFMA_X8 1
#else
#define HAVE_MFMA_X8 0
#endif

#if __has_builtin(__builtin_amdgcn_permlane32_swap)
#define HAVE_PERMLANE32 1
#else
#define HAVE_PERMLANE32 0
#endif

static __device__ __forceinline__ float max3f(float a, float b, float c) {
    return fmaxf(fmaxf(a, b), c);   // fuses to v_max3_f32
}

// 16-element register max as a max3 tree
static __device__ __forceinline__ float redmax16(const f32x16& a) {
    float x0 = max3f(a[0],  a[1],  a[2]);
    float x1 = max3f(a[3],  a[4],  a[5]);
    float x2 = max3f(a[6],  a[7],  a[8]);
    float x3 = max3f(a[9],  a[10], a[11]);
    float x4 = max3f(a[12], a[13], a[14]);
    float y0 = max3f(x0, x1, x2);
    float y1 = max3f(x3, x4, a[15]);
    return fmaxf(y0, y1);
}

// max with the value from lane^32, on the VALU (v_permlane32_swap) instead of
// an LDS bpermute — shorter per-pair critical chain, no LDS-pipe traffic.
static __device__ __forceinline__ float halfmax(float m) {
#if HAVE_PERMLANE32
    i32x2 pr = __builtin_amdgcn_permlane32_swap(__builtin_bit_cast(int, m),
                                                __builtin_bit_cast(int, m),
                                                false, false);
    return fmaxf(__builtin_bit_cast(float, pr[0]), __builtin_bit_cast(float, pr[1]));
#else
    return fmaxf(m, __shfl_xor(m, 32));
#endif
}

#if HAVE_MFMA_X8
static __device__ __forceinline__ short f2bfbits(float x) {
    __bf16 b = (__bf16)x;
    return __builtin_bit_cast(short, b);
}
#endif

// R3: latency/occupancy round. R2 showed no pipe >50% busy and occupancy ~30%
// (VALU 47 / MFMA 32 / LDS ~35): latency-bound. Changes:
//  (a) 512-thread blocks, 8 q per block: LDS 40KB -> 4 blocks/CU -> 32 waves/CU
//      (100% cap, was 62%); staging cost per wave halves.
//  (b) permlane32_swap for both half-combines (VALU, was LDS bpermute).
//  (c) grid transposed (qg on x, kc on y): consecutively-dispatched blocks share
//      the same staged K chunk -> same 48KB hot in each XCD's L2.
__global__ __launch_bounds__(512, 4) void matcher_kernel(const float* __restrict__ tgt,
                                                         const float* __restrict__ mem,
                                                         float* __restrict__ out)
{
    // K fragments: per k, chunk0 = 64 lanes x 16B (d0-15), chunk1 = 32 rows x 16B
    // (d16-23). 1536B per k. 24 KB total.
    __shared__ __align__(16) __bf16 Kf[KCH * 768];
    // Per-wave epilogue buffer: [pair][32 swizzled maxes]. 2 KB per wave, 16 KB.
    __shared__ float vbuf[WPB][KCH * 32];

    const int tid = threadIdx.x;
    const int qg  = blockIdx.x;   // 0..15  (8 q's per block)
    const int kc  = blockIdx.y;   // 0..127
    const int k0  = kc * KCH;

    // ---- stage K chunk: fp32 -> bf16, MFMA fragment order (1 row/thread) ----
    {
        const int r  = tid;            // 512 threads == KCH*SL rows exactly
        const int kl = r >> 5;
        const int s  = r & 31;
        const float* src = mem + (size_t)(k0 + kl) * D5 + s * ZD;
        float tv[24];
#pragma unroll
        for (int j = 0; j < 6; ++j) ((float4*)tv)[j] = ((const float4*)src)[j];
        bf16x8 a, b, c;
#pragma unroll
        for (int j = 0; j < 8; ++j) {
            a[j] = (__bf16)tv[j];
            b[j] = (__bf16)tv[8 + j];
            c[j] = (__bf16)tv[16 + j];
        }
        __bf16* base = Kf + kl * 768;
        *(bf16x8*)(base +        s * 8)  = a;  // chunk0, lane s      (d 0-7)
        *(bf16x8*)(base + (32 +  s) * 8) = b;  // chunk0, lane s+32   (d 8-15)
        *(bf16x8*)(base + 512 +  s * 8)  = c;  // chunk1, row s       (d 16-23)
    }

    // ---- per-wave Q fragments (registers, live across the whole k-loop) ----
    const int lane = tid & 63;
    const int wv   = tid >> 6;   // 0..7
    const int t    = lane & 31;
    const int h    = lane >> 5;
    const int q    = qg * WPB + wv;

    const float4* p4 = (const float4*)(tgt + (size_t)q * D5 + t * ZD);
    bf16x8 aQ0;
    {
        float4 u0 = p4[2 * h], u1 = p4[2 * h + 1];  // d = h*8 .. h*8+7
        aQ0[0] = (__bf16)u0.x; aQ0[1] = (__bf16)u0.y; aQ0[2] = (__bf16)u0.z; aQ0[3] = (__bf16)u0.w;
        aQ0[4] = (__bf16)u1.x; aQ0[5] = (__bf16)u1.y; aQ0[6] = (__bf16)u1.z; aQ0[7] = (__bf16)u1.w;
    }
#if HAVE_MFMA_X8
    // 32x32x8 A/B fragment: lane holds k = h*4 + j, i.e. d = 16 + h*4 + j.
    s16x4 aQ1;
    {
        float4 w = p4[4 + h];                       // d16-19 (h=0) / d20-23 (h=1)
        aQ1[0] = f2bfbits(w.x); aQ1[1] = f2bfbits(w.y);
        aQ1[2] = f2bfbits(w.z); aQ1[3] = f2bfbits(w.w);
    }
#else
    bf16x8 aQ1;
    if (h == 0) {
        float4 w0 = p4[4], w1 = p4[5];              // d = 16..23
        aQ1[0] = (__bf16)w0.x; aQ1[1] = (__bf16)w0.y; aQ1[2] = (__bf16)w0.z; aQ1[3] = (__bf16)w0.w;
        aQ1[4] = (__bf16)w1.x; aQ1[5] = (__bf16)w1.y; aQ1[6] = (__bf16)w1.z; aQ1[7] = (__bf16)w1.w;
    } else {
#pragma unroll
        for (int j = 0; j < 8; ++j) aQ1[j] = (__bf16)0.0f; // d 24-31 pad
    }
#endif

    f32x16 zacc;
#pragma unroll
    for (int i = 0; i < 16; ++i) zacc[i] = 0.0f;

    __syncthreads();

    float* vb = vbuf[wv];

    // ---- pair loop: this wave handles (q, k0+kl) for kl = 0..KCH-1 ----
#pragma unroll
    for (int kl = 0; kl < KCH; ++kl) {
        const __bf16* lb = Kf + kl * 768;
        bf16x8 bK0 = *(const bf16x8*)(lb + lane * 8);
#if HAVE_MFMA_X8
        // tail fragment: K[s=t][16 + h*4 + j], 8B per lane, all lanes valid
        s16x4 bK1 = *(const s16x4*)(lb + 512 + t * 8 + h * 4);

        // S[t][s]: A=Q (m=t), B=K (n=s)
        f32x16 accS = __builtin_amdgcn_mfma_f32_32x32x16_bf16(aQ0, bK0, zacc, 0, 0, 0);
        accS = __builtin_amdgcn_mfma_f32_32x32x8bf16_1k(aQ1, bK1, accS, 0, 0, 0);
        // S^T[s][t]: A=K (m=s), B=Q (n=t)
        f32x16 accT = __builtin_amdgcn_mfma_f32_32x32x16_bf16(bK0, aQ0, zacc, 0, 0, 0);
        accT = __builtin_amdgcn_mfma_f32_32x32x8bf16_1k(bK1, aQ1, accT, 0, 0, 0);
#else
        bf16x8 bK1 = *(const bf16x8*)(lb + 512 + t * 8);

        f32x16 accS = __builtin_amdgcn_mfma_f32_32x32x16_bf16(aQ0, bK0, zacc, 0, 0, 0);
        accS        = __builtin_amdgcn_mfma_f32_32x32x16_bf16(aQ1, bK1, accS, 0, 0, 0);
        f32x16 accT = __builtin_amdgcn_mfma_f32_32x32x16_bf16(bK0, aQ0, zacc, 0, 0, 0);
        accT        = __builtin_amdgcn_mfma_f32_32x32x16_bf16(bK1, aQ1, accT, 0, 0, 0);
#endif
        // accS: col=s=lane&31, regs+halves span t -> max over t = score.max(axis=3)
        // accT: col=t=lane&31, regs+halves span s -> max over s = score.max(axis=2)
        float m1 = halfmax(redmax16(accS));
        float m2 = halfmax(redmax16(accT));
        float v = m1 + m2;                    // per-lane: axis3max[s] + axis2max[t]
        // XOR-swizzled store: pair kl, slot t -> word kl*32 + (t^kl). Conflict-free.
        if (h == 0) vb[(kl << 5) + (t ^ kl)] = v;
    }

    // ---- batched final phase (per wave, no barrier: same-wave LDS reuse) ----
    // Pair p's 32 values summed by lane pair (p, p+16); lanes 32-63 duplicate.
    {
        const int p    = lane & 15;
        const int half = (lane >> 4) & 1;
        float x[16];
#pragma unroll
        for (int i = 0; i < 16; ++i)
            x[i] = vb[(p << 5) + ((half << 4) + i ^ p)];  // conflict-free scalar reads
        // pairwise add tree (full ILP)
        float s0 = (x[0] + x[1]) + (x[2] + x[3]);
        float s1 = (x[4] + x[5]) + (x[6] + x[7]);
        float s2 = (x[8] + x[9]) + (x[10] + x[11]);
        float s3 = (x[12] + x[13]) + (x[14] + x[15]);
        float sum = (s0 + s1) + (s2 + s3);
        sum += __shfl_xor(sum, 16);           // combine halves of the 32-sum
        float r = 1.0f / (1.0f + __expf(-sum * (1.0f / 64.0f)));
        if (lane < 16) {
            const int idx = q * KN + k0 + p;
            out[idx] = r;                     // output 0
            out[idx + QN * KN] = r;           // output 1 (tuple repeats score_p)
        }
    }
}

extern "C" void kernel_launch(void* const* d_in, const int* in_sizes, int n_in,
                              void* d_out, int out_size, void* d_ws, size_t ws_size,
                              hipStream_t stream)
{
    const float* tgt = (const float*)d_in[0];
    const float* mem = (const float*)d_in[1];
    float* out = (float*)d_out;
    dim3 grid(QN / WPB, KN / KCH);
    matcher_kernel<<<grid, 512, 0, stream>>>(tgt, mem, out);
}

// Round 4
// 89.642 us; speedup vs baseline: 1.0889x; 1.0284x over previous
//
#include <hip/hip_runtime.h>
#include <hip/hip_bf16.h>

typedef __bf16 bf16x8 __attribute__((ext_vector_type(8)));
typedef short  s16x4  __attribute__((ext_vector_type(4)));
typedef float  f32x16 __attribute__((ext_vector_type(16)));
typedef int    i32x2  __attribute__((ext_vector_type(2)));

constexpr int QN  = 128;   // query rows
constexpr int KN  = 2048;  // memory rows
constexpr int D5  = 768;
constexpr int SL  = 32;    // seq_len (t and s extent)
constexpr int ZD  = 24;    // per-token sub-dim
constexpr int KCH = 16;    // k's per block
constexpr int WPB = 8;     // waves per block

#if __has_builtin(__builtin_amdgcn_mfma_f32_32x32x8bf16_1k)
#define HAVE_MFMA_X8 1
#else
#define HAVE_MFMA_X8 0
#endif

#if __has_builtin(__builtin_amdgcn_permlane32_swap)
#define HAVE_PERMLANE32 1
#else
#define HAVE_PERMLANE32 0
#endif

static __device__ __forceinline__ float max3f(float a, float b, float c) {
    return fmaxf(fmaxf(a, b), c);   // fuses to v_max3_f32
}

// 16-element register max as a max3 tree
static __device__ __forceinline__ float redmax16(const f32x16& a) {
    float x0 = max3f(a[0],  a[1],  a[2]);
    float x1 = max3f(a[3],  a[4],  a[5]);
    float x2 = max3f(a[6],  a[7],  a[8]);
    float x3 = max3f(a[9],  a[10], a[11]);
    float x4 = max3f(a[12], a[13], a[14]);
    float y0 = max3f(x0, x1, x2);
    float y1 = max3f(x3, x4, a[15]);
    return fmaxf(y0, y1);
}

// max with the value from lane^32, on the VALU (v_permlane32_swap) instead of
// an LDS bpermute.
static __device__ __forceinline__ float halfmax(float m) {
#if HAVE_PERMLANE32
    i32x2 pr = __builtin_amdgcn_permlane32_swap(__builtin_bit_cast(int, m),
                                                __builtin_bit_cast(int, m),
                                                false, false);
    return fmaxf(__builtin_bit_cast(float, pr[0]), __builtin_bit_cast(float, pr[1]));
#else
    return fmaxf(m, __shfl_xor(m, 32));
#endif
}

#if HAVE_MFMA_X8
static __device__ __forceinline__ short f2bfbits(float x) {
    __bf16 b = (__bf16)x;
    return __builtin_bit_cast(short, b);
}
#endif

// R4: occupancy round. R0-R3 all sat at ~30% occupancy / ~40us regardless of
// micro-opts -> latency wall. VGPR_Count=44 only shows ARCH vgprs; the
// unroll-16 pair loop lets the scheduler keep many 32-reg AGPR accumulator
// sets live, blowing the unified register budget and capping residency at
// ~3 waves/SIMD. Fix: (a) __launch_bounds__(512, 8) contracts the allocator
// to <=256 unified regs/wave (>=8 waves/SIMD); (b) #pragma unroll 4 bounds
// live accumulators (~200 regs incl. operands) so the cap is met without
// scratch spills while keeping 4 independent MFMA chains in flight.
__global__ __launch_bounds__(512, 8) void matcher_kernel(const float* __restrict__ tgt,
                                                         const float* __restrict__ mem,
                                                         float* __restrict__ out)
{
    // K fragments: per k, chunk0 = 64 lanes x 16B (d0-15), chunk1 = 32 rows x 16B
    // (d16-23). 1536B per k. 24 KB total.
    __shared__ __align__(16) __bf16 Kf[KCH * 768];
    // Per-wave epilogue buffer: [pair][32 swizzled maxes]. 2 KB per wave, 16 KB.
    __shared__ float vbuf[WPB][KCH * 32];

    const int tid = threadIdx.x;
    const int qg  = blockIdx.x;   // 0..15  (8 q's per block)
    const int kc  = blockIdx.y;   // 0..127
    const int k0  = kc * KCH;

    // ---- stage K chunk: fp32 -> bf16, MFMA fragment order (1 row/thread) ----
    {
        const int r  = tid;            // 512 threads == KCH*SL rows exactly
        const int kl = r >> 5;
        const int s  = r & 31;
        const float* src = mem + (size_t)(k0 + kl) * D5 + s * ZD;
        float tv[24];
#pragma unroll
        for (int j = 0; j < 6; ++j) ((float4*)tv)[j] = ((const float4*)src)[j];
        bf16x8 a, b, c;
#pragma unroll
        for (int j = 0; j < 8; ++j) {
            a[j] = (__bf16)tv[j];
            b[j] = (__bf16)tv[8 + j];
            c[j] = (__bf16)tv[16 + j];
        }
        __bf16* base = Kf + kl * 768;
        *(bf16x8*)(base +        s * 8)  = a;  // chunk0, lane s      (d 0-7)
        *(bf16x8*)(base + (32 +  s) * 8) = b;  // chunk0, lane s+32   (d 8-15)
        *(bf16x8*)(base + 512 +  s * 8)  = c;  // chunk1, row s       (d 16-23)
    }

    // ---- per-wave Q fragments (registers, live across the whole k-loop) ----
    const int lane = tid & 63;
    const int wv   = tid >> 6;   // 0..7
    const int t    = lane & 31;
    const int h    = lane >> 5;
    const int q    = qg * WPB + wv;

    const float4* p4 = (const float4*)(tgt + (size_t)q * D5 + t * ZD);
    bf16x8 aQ0;
    {
        float4 u0 = p4[2 * h], u1 = p4[2 * h + 1];  // d = h*8 .. h*8+7
        aQ0[0] = (__bf16)u0.x; aQ0[1] = (__bf16)u0.y; aQ0[2] = (__bf16)u0.z; aQ0[3] = (__bf16)u0.w;
        aQ0[4] = (__bf16)u1.x; aQ0[5] = (__bf16)u1.y; aQ0[6] = (__bf16)u1.z; aQ0[7] = (__bf16)u1.w;
    }
#if HAVE_MFMA_X8
    // 32x32x8 A/B fragment: lane holds k = h*4 + j, i.e. d = 16 + h*4 + j.
    s16x4 aQ1;
    {
        float4 w = p4[4 + h];                       // d16-19 (h=0) / d20-23 (h=1)
        aQ1[0] = f2bfbits(w.x); aQ1[1] = f2bfbits(w.y);
        aQ1[2] = f2bfbits(w.z); aQ1[3] = f2bfbits(w.w);
    }
#else
    bf16x8 aQ1;
    if (h == 0) {
        float4 w0 = p4[4], w1 = p4[5];              // d = 16..23
        aQ1[0] = (__bf16)w0.x; aQ1[1] = (__bf16)w0.y; aQ1[2] = (__bf16)w0.z; aQ1[3] = (__bf16)w0.w;
        aQ1[4] = (__bf16)w1.x; aQ1[5] = (__bf16)w1.y; aQ1[6] = (__bf16)w1.z; aQ1[7] = (__bf16)w1.w;
    } else {
#pragma unroll
        for (int j = 0; j < 8; ++j) aQ1[j] = (__bf16)0.0f; // d 24-31 pad
    }
#endif

    f32x16 zacc;
#pragma unroll
    for (int i = 0; i < 16; ++i) zacc[i] = 0.0f;

    __syncthreads();

    float* vb = vbuf[wv];

    // ---- pair loop: this wave handles (q, k0+kl) for kl = 0..KCH-1 ----
    // unroll 4: bounded live-accumulator footprint (fits 256-reg cap), still
    // 4 independent MFMA chains per wave for ILP.
#pragma unroll 4
    for (int kl = 0; kl < KCH; ++kl) {
        const __bf16* lb = Kf + kl * 768;
        bf16x8 bK0 = *(const bf16x8*)(lb + lane * 8);
#if HAVE_MFMA_X8
        // tail fragment: K[s=t][16 + h*4 + j], 8B per lane, all lanes valid
        s16x4 bK1 = *(const s16x4*)(lb + 512 + t * 8 + h * 4);

        // S[t][s]: A=Q (m=t), B=K (n=s)
        f32x16 accS = __builtin_amdgcn_mfma_f32_32x32x16_bf16(aQ0, bK0, zacc, 0, 0, 0);
        accS = __builtin_amdgcn_mfma_f32_32x32x8bf16_1k(aQ1, bK1, accS, 0, 0, 0);
        // S^T[s][t]: A=K (m=s), B=Q (n=t)
        f32x16 accT = __builtin_amdgcn_mfma_f32_32x32x16_bf16(bK0, aQ0, zacc, 0, 0, 0);
        accT = __builtin_amdgcn_mfma_f32_32x32x8bf16_1k(bK1, aQ1, accT, 0, 0, 0);
#else
        bf16x8 bK1 = *(const bf16x8*)(lb + 512 + t * 8);

        f32x16 accS = __builtin_amdgcn_mfma_f32_32x32x16_bf16(aQ0, bK0, zacc, 0, 0, 0);
        accS        = __builtin_amdgcn_mfma_f32_32x32x16_bf16(aQ1, bK1, accS, 0, 0, 0);
        f32x16 accT = __builtin_amdgcn_mfma_f32_32x32x16_bf16(bK0, aQ0, zacc, 0, 0, 0);
        accT        = __builtin_amdgcn_mfma_f32_32x32x16_bf16(bK1, aQ1, accT, 0, 0, 0);
#endif
        // accS: col=s=lane&31, regs+halves span t -> max over t = score.max(axis=3)
        // accT: col=t=lane&31, regs+halves span s -> max over s = score.max(axis=2)
        float m1 = halfmax(redmax16(accS));
        float m2 = halfmax(redmax16(accT));
        float v = m1 + m2;                    // per-lane: axis3max[s] + axis2max[t]
        // XOR-swizzled store: pair kl, slot t -> word kl*32 + (t^kl). Conflict-free.
        if (h == 0) vb[(kl << 5) + (t ^ kl)] = v;
    }

    // ---- batched final phase (per wave, no barrier: same-wave LDS reuse) ----
    // Pair p's 32 values summed by lane pair (p, p+16); lanes 32-63 duplicate.
    {
        const int p    = lane & 15;
        const int half = (lane >> 4) & 1;
        float x[16];
#pragma unroll
        for (int i = 0; i < 16; ++i)
            x[i] = vb[(p << 5) + ((half << 4) + i ^ p)];  // conflict-free scalar reads
        // pairwise add tree (full ILP)
        float s0 = (x[0] + x[1]) + (x[2] + x[3]);
        float s1 = (x[4] + x[5]) + (x[6] + x[7]);
        float s2 = (x[8] + x[9]) + (x[10] + x[11]);
        float s3 = (x[12] + x[13]) + (x[14] + x[15]);
        float sum = (s0 + s1) + (s2 + s3);
        sum += __shfl_xor(sum, 16);           // combine halves of the 32-sum
        float r = 1.0f / (1.0f + __expf(-sum * (1.0f / 64.0f)));
        if (lane < 16) {
            const int idx = q * KN + k0 + p;
            out[idx] = r;                     // output 0
            out[idx + QN * KN] = r;           // output 1 (tuple repeats score_p)
        }
    }
}

extern "C" void kernel_launch(void* const* d_in, const int* in_sizes, int n_in,
                              void* d_out, int out_size, void* d_ws, size_t ws_size,
                              hipStream_t stream)
{
    const float* tgt = (const float*)d_in[0];
    const float* mem = (const float*)d_in[1];
    float* out = (float*)d_out;
    dim3 grid(QN / WPB, KN / KCH);
    matcher_kernel<<<grid, 512, 0, stream>>>(tgt, mem, out);
}